// Round 9
// baseline (30936.755 us; speedup 1.0000x reference)
//
#include <hip/hip_runtime.h>
#include <cstdint>
#include <cstddef>

// ---------------- problem constants ----------------
#define TSTEPS 2000
#define NB     256      // batch
#define HID    128
#define CIN    14
#define NGRP   128      // 2-row groups
#define RG     2

// ---------------- workspace layout (bytes) ----------------
#define OFF_FLG  0ull                      // [128 g][4 q] * 32B = 16384
#define OFF_M1   16384ull                  // [2][128][2r][128h] f32 = 262144
#define OFF_M2   (OFF_M1 + 262144ull)      // [2][128][2r][128h] f32
#define OFF_SPK  (OFF_M2 + 262144ull)      // [2][128][8w] u32 = 8192
#define OFF_FEAT (OFF_SPK + 8192ull)       // [256][128] f32 = 131072
#define OFF_AB   (OFF_FEAT + 131072ull)    // a[64], b[64] = 512
#define OFF_PART (OFF_AB + 512ull)         // [2304][64][2] f32 = 1179648
#define OFF_MASK (OFF_PART + 1179648ull)   // [2000][256] u64 = 4096000
#define ZERO_WORDS 137216                  // flags + m1 + m2 + spk

// ============================================================
// K0: zero flags + state buffers (every launch, for graph replay)
// ============================================================
__global__ __launch_bounds__(256) void k0_zero(unsigned* ws) {
  int i = blockIdx.x * 256 + threadIdx.x;
  if (i < ZERO_WORDS) ws[i] = 0u;
}

// ============================================================
// K1: conv1d -> per-(b,tile) partial sum/sumsq for BN
// ============================================================
__global__ __launch_bounds__(256) void k1_stats(const float* __restrict__ x,
                                                const float* __restrict__ cw,
                                                float* __restrict__ part) {
  __shared__ float xLds[244 * CIN];
  __shared__ float cwLds[64 * 70];
  __shared__ float red[2][4][64];
  const int b = blockIdx.x, tile = blockIdx.y;
  const int base = tile * 240;
  for (int f = threadIdx.x; f < 244 * CIN; f += 256) {
    int u = f / CIN, ci = f - u * CIN;
    int tp = base + u - 2;
    xLds[f] = (tp >= 0 && tp < TSTEPS) ? x[((size_t)tp * NB + b) * CIN + ci] : 0.0f;
  }
  for (int f = threadIdx.x; f < 64 * 70; f += 256) cwLds[f] = cw[f];
  __syncthreads();

  const int co = threadIdx.x & 63, tq = threadIdx.x >> 6;
  float cwr[70];
#pragma unroll
  for (int s = 0; s < 70; ++s) cwr[s] = cwLds[co * 70 + s];
  float xw[5][CIN];
  const int u0 = tq * 60;
#pragma unroll
  for (int r = 0; r < 4; ++r)
#pragma unroll
    for (int ci = 0; ci < CIN; ++ci) xw[r][ci] = xLds[(u0 + r) * CIN + ci];

  float s1 = 0.0f, s2 = 0.0f;
  const int tbase = base + tq * 60;
  for (int i5 = 0; i5 < 60; i5 += 5) {
#pragma unroll
    for (int s = 0; s < 5; ++s) {
#pragma unroll
      for (int ci = 0; ci < CIN; ++ci)
        xw[(s + 4) % 5][ci] = xLds[(u0 + i5 + s + 4) * CIN + ci];
      float y = 0.0f;
#pragma unroll
      for (int kk = 0; kk < 5; ++kk)
#pragma unroll
        for (int ci = 0; ci < CIN; ++ci)
          y += xw[(s + kk) % 5][ci] * cwr[ci * 5 + kk];
      if (tbase + i5 + s < TSTEPS) { s1 += y; s2 += y * y; }
    }
  }
  red[0][tq][co] = s1; red[1][tq][co] = s2;
  __syncthreads();
  if (threadIdx.x < 64) {
    float a1 = red[0][0][co] + red[0][1][co] + red[0][2][co] + red[0][3][co];
    float a2 = red[1][0][co] + red[1][1][co] + red[1][2][co] + red[1][3][co];
    int blk = tile * NB + b;
    part[blk * 128 + co * 2 + 0] = a1;
    part[blk * 128 + co * 2 + 1] = a2;
  }
}

// K1b: deterministic fixed-order reduction of partials -> a[co], b[co]
__global__ __launch_bounds__(256) void k1b_reduce(const float* __restrict__ gamma,
                           const float* __restrict__ beta,
                           const float* __restrict__ part, float* __restrict__ ab) {
  __shared__ float red[2][4][64];
  const int co = threadIdx.x & 63, pt = threadIdx.x >> 6;
  float s1 = 0.0f, s2 = 0.0f;
  for (int blk = pt * 576; blk < pt * 576 + 576; ++blk) {
    s1 += part[blk * 128 + co * 2 + 0];
    s2 += part[blk * 128 + co * 2 + 1];
  }
  red[0][pt][co] = s1; red[1][pt][co] = s2;
  __syncthreads();
  if (threadIdx.x < 64) {
    float a1 = red[0][0][co] + red[0][1][co] + red[0][2][co] + red[0][3][co];
    float a2 = red[1][0][co] + red[1][1][co] + red[1][2][co] + red[1][3][co];
    const float N = (float)TSTEPS * (float)NB;
    float mu = a1 / N;
    float var = a2 / N - mu * mu;
    float rstd = 1.0f / sqrtf(var + 1e-5f);
    float a = gamma[co] * rstd;
    ab[co] = a;
    ab[64 + co] = beta[co] - mu * a;
  }
}

// ============================================================
// K2: conv1d -> BN -> spike -> pack 64 channel bits into u64 per (t,b)
// ============================================================
__global__ __launch_bounds__(256) void k2_spike(const float* __restrict__ x,
                                                const float* __restrict__ cw,
                                                const float* __restrict__ thrp,
                                                const float* __restrict__ ab,
                                                unsigned long long* __restrict__ masks) {
  __shared__ float xLds[244 * CIN];
  __shared__ float cwLds[64 * 70];
  const int b = blockIdx.x, tile = blockIdx.y;
  const int base = tile * 240;
  for (int f = threadIdx.x; f < 244 * CIN; f += 256) {
    int u = f / CIN, ci = f - u * CIN;
    int tp = base + u - 2;
    xLds[f] = (tp >= 0 && tp < TSTEPS) ? x[((size_t)tp * NB + b) * CIN + ci] : 0.0f;
  }
  for (int f = threadIdx.x; f < 64 * 70; f += 256) cwLds[f] = cw[f];
  __syncthreads();

  const int co = threadIdx.x & 63, tq = threadIdx.x >> 6;
  const float thr = thrp[0];
  const float aC = ab[co], bC = ab[64 + co];
  float cwr[70];
#pragma unroll
  for (int s = 0; s < 70; ++s) cwr[s] = cwLds[co * 70 + s];
  float xw[5][CIN];
  const int u0 = tq * 60;
#pragma unroll
  for (int r = 0; r < 4; ++r)
#pragma unroll
    for (int ci = 0; ci < CIN; ++ci) xw[r][ci] = xLds[(u0 + r) * CIN + ci];

  const int tbase = base + tq * 60;
  for (int i5 = 0; i5 < 60; i5 += 5) {
#pragma unroll
    for (int s = 0; s < 5; ++s) {
#pragma unroll
      for (int ci = 0; ci < CIN; ++ci)
        xw[(s + 4) % 5][ci] = xLds[(u0 + i5 + s + 4) * CIN + ci];
      float y = 0.0f;
#pragma unroll
      for (int kk = 0; kk < 5; ++kk)
#pragma unroll
        for (int ci = 0; ci < CIN; ++ci)
          y += xw[(s + kk) % 5][ci] * cwr[ci * 5 + kk];
      int t = tbase + i5 + s;
      if (t < TSTEPS) {
        float bn = y * aC + bC;
        unsigned long long m = __ballot(bn - thr > 0.0f);  // lane i = channel i
        if (co == 0) masks[(size_t)t * NB + b] = m;
      }
    }
  }
}

// ============================================================
// KP: persistent two-layer SLSTM, two-group interleave (r8 schedule),
// with ANTI-IDLE sync:
//  - wave1 lanes 0-3 poll the L3 flags, publish to LDS gflag; ALL 512
//    threads spin on gflag while burning v_fmac (keeps DPM clocks up,
//    LDS-speed release).
//  - publish-drain is wave0-local (cells live in wave0): s_waitcnt
//    vmcnt(0) + flag store, no block barrier.
//  - 96KB dynamic LDS -> exactly 1 block/CU (burn waves never steal
//    VALU from a co-resident block). 256 blocks on 256 CUs.
// Arithmetic bit-identical to r8 (absmax 0.0).
// ============================================================
__device__ __forceinline__ float sigm(float v) { return 1.0f / (1.0f + expf(-v)); }

__device__ __forceinline__ void _burn(float& x) {
#pragma unroll
  for (int i = 0; i < 32; ++i)
    asm volatile("v_fmac_f32 %0, %0, %0" : "+v"(x));
}

__device__ __forceinline__ void do_gemms(const float* A1x, const float* A2x,
    float* g1x, float* g2x,
    const float wr1[2][2][12], const float wr2[2][2][16],
    int kq, int j0) {
  float a100 = 0, a101 = 0, a110 = 0, a111 = 0;
  const float4* v1 = (const float4*)A1x;
#pragma unroll
  for (int m = 0; m < 12; ++m) {
    float4 av = v1[m * 8 + kq];
    a100 += wr1[0][0][m] * av.x; a101 += wr1[0][0][m] * av.y;
    a110 += wr1[1][0][m] * av.x; a111 += wr1[1][0][m] * av.y;
    a100 += wr1[0][1][m] * av.z; a101 += wr1[0][1][m] * av.w;
    a110 += wr1[1][1][m] * av.z; a111 += wr1[1][1][m] * av.w;
  }
  float a200 = 0, a201 = 0, a210 = 0, a211 = 0;
  const float4* v2 = (const float4*)A2x;
#pragma unroll
  for (int m = 0; m < 16; ++m) {
    float4 av = v2[m * 8 + kq];
    a200 += wr2[0][0][m] * av.x; a201 += wr2[0][0][m] * av.y;
    a210 += wr2[1][0][m] * av.x; a211 += wr2[1][0][m] * av.y;
    a200 += wr2[0][1][m] * av.z; a201 += wr2[0][1][m] * av.w;
    a210 += wr2[1][1][m] * av.z; a211 += wr2[1][1][m] * av.w;
  }
#define RED3(v) v += __shfl_xor(v, 8); v += __shfl_xor(v, 16); v += __shfl_xor(v, 32)
  RED3(a100); RED3(a101); RED3(a110); RED3(a111);
  RED3(a200); RED3(a201); RED3(a210); RED3(a211);
#undef RED3
  if (kq == 0) {
    *(float4*)&g1x[j0 * 2] = make_float4(a100, a101, a110, a111);
    *(float4*)&g2x[j0 * 2] = make_float4(a200, a201, a210, a211);
  }
}

__global__ __launch_bounds__(512) void kp_fused(char* ws,
    const float* __restrict__ w_ih1, const float* __restrict__ w_hh1,
    const float* __restrict__ b_ih1, const float* __restrict__ b_hh1,
    const float* __restrict__ thr1p,
    const float* __restrict__ w_ih2, const float* __restrict__ w_hh2,
    const float* __restrict__ b_ih2, const float* __restrict__ b_hh2,
    const float* __restrict__ thr2p) {
  extern __shared__ float dyn[];           // 96KB requested (occupancy clamp)
  float* A1a = dyn;                        // [192k][2r] = 384
  float* A2a = dyn + 384;                  // [256k][2r] = 512
  float* A1b = dyn + 896;                  // 384
  float* A2b = dyn + 1280;                 // 512
  __shared__ __align__(16) float g1a[256], g2a[256], g1b[256], g2b[256];
  __shared__ float bias1[128], bias2[128];
  __shared__ unsigned gfa[4], gfb[4];      // LDS mirror of the 4 clique flags

  const int tid = threadIdx.x;
  const int bid = blockIdx.x;
  const int q = bid >> 6;                 // h-quarter
  const int gA = (bid & 63) * 2, gB = gA + 1;
  const int lane = tid & 63, wv = tid >> 6;
  const int u = lane & 7, kq = lane >> 3; // 8-way k-pair split
  const int jp = wv * 8 + u;              // 0..63 -> 2 gate rows each
  const int j0 = jp * 2;

  unsigned* flags = (unsigned*)(ws + OFF_FLG);
  float* m1ws = (float*)(ws + OFF_M1);
  float* m2ws = (float*)(ws + OFF_M2);
  unsigned* spkw = (unsigned*)(ws + OFF_SPK);
  float* feat = (float*)(ws + OFF_FEAT);
  const unsigned long long* masks = (const unsigned long long*)(ws + OFF_MASK);

  // ---- one-time: weights -> registers; k = (m*8+kq)*2 + kk ----
  float wr1[2][2][12], wr2[2][2][16];
#pragma unroll
  for (int jj = 0; jj < 2; ++jj) {
    const int j = j0 + jj;
    const int a = j >> 5, hl = j & 31;
    const int grow = a * 128 + q * 32 + hl;
#pragma unroll
    for (int m = 0; m < 12; ++m)
#pragma unroll
      for (int kk = 0; kk < 2; ++kk) {
        int k = (m * 8 + kq) * 2 + kk;
        wr1[jj][kk][m] = (k < 64) ? w_ih1[grow * 64 + k]
                                  : w_hh1[grow * 128 + (k - 64)];
      }
#pragma unroll
    for (int m = 0; m < 16; ++m)
#pragma unroll
      for (int kk = 0; kk < 2; ++kk) {
        int k = (m * 8 + kq) * 2 + kk;
        wr2[jj][kk][m] = (k < 128) ? w_ih2[grow * 128 + k]
                                   : w_hh2[grow * 128 + (k - 128)];
      }
  }
  if (tid < 128) {
    int a = tid >> 5, hl = tid & 31;
    int gr = a * 128 + q * 32 + hl;
    bias1[tid] = b_ih1[gr] + b_hh1[gr];
    bias2[tid] = b_ih2[gr] + b_hh2[gr];
  }
  if (tid < 4) { gfa[tid] = 0u; gfb[tid] = 0u; }
  const float thr1 = thr1p[0], thr2 = thr2p[0];
  float sy1a = 0, me1a = 0, sy2a = 0, me2a = 0, fca = 0;
  float sy1b = 0, me1b = 0, sy2b = 0, me2b = 0, fcb = 0;
  float sm1a = 0, sm2a = 0, sm1b = 0, sm2b = 0;
  unsigned sspa = 0, sspb = 0;
  unsigned long long mka = 0, mkb = 0;
  __syncthreads();

// ---- macros (staging/cells identical to r8) ----
#define ISSUE(gX, pp, sm1, sm2, ssp, smk)                                      \
  {                                                                            \
    const int par = ((pp) + 1) & 1;                                            \
    const int wpar = (pp) & 1;                                                 \
    if (tid < 128) {                                                           \
      int tmask = ((pp) < TSTEPS) ? (pp) : (TSTEPS - 1);                       \
      smk = masks[(size_t)tmask * NB + (gX) * 2 + (tid & 1)];                  \
    }                                                                          \
    if (tid >= 128 && tid < 384)                                               \
      sm1 = __hip_atomic_load(                                                 \
          &m1ws[((size_t)(par * 128 + (gX)) * 2 + (tid & 1)) * 128 +           \
                ((tid >> 1) - 64)],                                            \
          __ATOMIC_RELAXED, __HIP_MEMORY_SCOPE_AGENT);                         \
    if (tid < 256)                                                             \
      ssp = __hip_atomic_load(                                                 \
          &spkw[(size_t)(par * 128 + (gX)) * 8 + (tid & 1) * 4 +               \
                ((tid >> 1) >> 5)],                                            \
          __ATOMIC_RELAXED, __HIP_MEMORY_SCOPE_AGENT);                         \
    else                                                                       \
      sm2 = __hip_atomic_load(                                                 \
          &m2ws[((size_t)(wpar * 128 + (gX)) * 2 + (tid & 1)) * 128 +          \
                ((tid >> 1) - 128)],                                           \
          __ATOMIC_RELAXED, __HIP_MEMORY_SCOPE_AGENT);                         \
  }

#define WRITESTG(A1x, A2x, sm1, sm2, ssp, smk)                                 \
  {                                                                            \
    if (tid < 128)      A1x[tid] = (float)((smk >> (tid >> 1)) & 1ull);        \
    else if (tid < 384) A1x[tid] = sm1;                                        \
    if (tid < 256)      A2x[tid] = (float)((ssp >> ((tid >> 1) & 31)) & 1u);   \
    else                A2x[tid] = sm2;                                        \
  }

#define DO_CELLS(gX, g1x, g2x, sy1, me1, sy2, me2, fc)                         \
  if (tid < 64) {                                                              \
    const int hl = tid & 31, rr = tid >> 5;                                    \
    if (p < TSTEPS) {                                                          \
      float gi = bias1[hl]        + g1x[hl * 2 + rr];                          \
      float gf = bias1[32 + hl]   + g1x[(32 + hl) * 2 + rr];                   \
      float gg = bias1[64 + hl]   + g1x[(64 + hl) * 2 + rr];                   \
      float go = bias1[96 + hl]   + g1x[(96 + hl) * 2 + rr];                   \
      float rst = (me1 - thr1 > 0.0f) ? thr1 : 0.0f;                           \
      float cn = sigm(gf) * sy1 + sigm(gi) * tanhf(gg);                        \
      float mn = sigm(go) * tanhf(cn) - rst;                                   \
      sy1 = cn; me1 = mn;                                                      \
      __hip_atomic_store(                                                      \
          &m1ws[((size_t)((p & 1) * 128 + (gX)) * 2 + rr) * 128 +              \
                (q * 32 + hl)],                                                \
          mn, __ATOMIC_RELAXED, __HIP_MEMORY_SCOPE_AGENT);                     \
      unsigned long long bal = __ballot(mn - thr1 > 0.0f);                     \
      if (lane == 0)                                                           \
        __hip_atomic_store(&spkw[(size_t)((p & 1) * 128 + (gX)) * 8 + q],      \
                           (unsigned)(bal & 0xffffffffull),                    \
                           __ATOMIC_RELAXED, __HIP_MEMORY_SCOPE_AGENT);        \
      if (lane == 32)                                                          \
        __hip_atomic_store(&spkw[(size_t)((p & 1) * 128 + (gX)) * 8 + 4 + q],  \
                           (unsigned)(bal >> 32),                              \
                           __ATOMIC_RELAXED, __HIP_MEMORY_SCOPE_AGENT);        \
    }                                                                          \
    if (p >= 1) {                                                              \
      float gi = bias2[hl]        + g2x[hl * 2 + rr];                          \
      float gf = bias2[32 + hl]   + g2x[(32 + hl) * 2 + rr];                   \
      float gg = bias2[64 + hl]   + g2x[(64 + hl) * 2 + rr];                   \
      float go = bias2[96 + hl]   + g2x[(96 + hl) * 2 + rr];                   \
      float rst = (me2 - thr2 > 0.0f) ? thr2 : 0.0f;                           \
      float cn = sigm(gf) * sy2 + sigm(gi) * tanhf(gg);                        \
      float mn = sigm(go) * tanhf(cn) - rst;                                   \
      sy2 = cn; me2 = mn;                                                      \
      __hip_atomic_store(                                                      \
          &m2ws[((size_t)(((p + 1) & 1) * 128 + (gX)) * 2 + rr) * 128 +        \
                (q * 32 + hl)],                                                \
          mn, __ATOMIC_RELAXED, __HIP_MEMORY_SCOPE_AGENT);                     \
      fc += mn;                                                                \
    }                                                                          \
  }

// wave0-local drain + flag: no block barrier needed (publishes are wave0's)
#define DRAIN_FLAG(gX, val)                                                    \
  if (tid < 64) {                                                              \
    asm volatile("s_waitcnt vmcnt(0)" ::: "memory");                           \
    if (tid == 0)                                                              \
      __hip_atomic_store(&flags[((size_t)(gX) * 4 + q) * 8], (unsigned)(val),  \
                         __ATOMIC_RELAXED, __HIP_MEMORY_SCOPE_AGENT);          \
  }

// wave1 lanes 0-3: poll L3 flags, mirror into LDS
#define GPOLL(gX, FL, val)                                                     \
  if (tid >= 64 && tid < 68) {                                                 \
    const int qq_ = tid - 64;                                                  \
    while (__hip_atomic_load(&flags[((size_t)(gX) * 4 + qq_) * 8],             \
                             __ATOMIC_RELAXED, __HIP_MEMORY_SCOPE_AGENT) <     \
           (unsigned)(val)) {}                                                 \
    (FL)[qq_] = (unsigned)(val);                                               \
  }

// all threads: burn-spin on the LDS mirror (keeps clocks up)
#define SPIN4(FL, val)                                                         \
  {                                                                            \
    volatile unsigned* vf_ = (FL);                                             \
    float bx_ = 1.0000001f;                                                    \
    while (vf_[0] < (unsigned)(val) || vf_[1] < (unsigned)(val) ||             \
           vf_[2] < (unsigned)(val) || vf_[3] < (unsigned)(val))               \
      _burn(bx_);                                                              \
    asm volatile("" ::: "memory");                                             \
  }

  // ---- prologue: issue both roles' phase-0 loads (state zeroed by k0) ----
  ISSUE(gA, 0, sm1a, sm2a, sspa, mka);
  ISSUE(gB, 0, sm1b, sm2b, sspb, mkb);
  __builtin_amdgcn_sched_barrier(0);

  for (int p = 0; p <= TSTEPS; ++p) {
    // ================= half A: group gA, phase p =================
    WRITESTG(A1a, A2a, sm1a, sm2a, sspa, mka);   // vmcnt waits land here
    __syncthreads();
    do_gemms(A1a, A2a, g1a, g2a, wr1, wr2, kq, j0);
    __syncthreads();
    DO_CELLS(gA, g1a, g2a, sy1a, me1a, sy2a, me2a, fca);
    if (p < TSTEPS) {
      DRAIN_FLAG(gA, p + 1);
      GPOLL(gA, gfa, p + 1);
      SPIN4(gfa, p + 1);
      ISSUE(gA, p + 1, sm1a, sm2a, sspa, mka);   // latency hides under half B
      __builtin_amdgcn_sched_barrier(0);
    }
    // ================= half B: group gB, phase p =================
    WRITESTG(A1b, A2b, sm1b, sm2b, sspb, mkb);
    __syncthreads();
    do_gemms(A1b, A2b, g1b, g2b, wr1, wr2, kq, j0);
    __syncthreads();
    DO_CELLS(gB, g1b, g2b, sy1b, me1b, sy2b, me2b, fcb);
    if (p < TSTEPS) {
      DRAIN_FLAG(gB, p + 1);
      GPOLL(gB, gfb, p + 1);
      SPIN4(gfb, p + 1);
      ISSUE(gB, p + 1, sm1b, sm2b, sspb, mkb);   // latency hides under half A
      __builtin_amdgcn_sched_barrier(0);
    }
  }

  if (tid < 64) {
    const int hl = tid & 31, rr = tid >> 5;
    feat[((size_t)gA * 2 + rr) * 128 + q * 32 + hl] = fca * (1.0f / (float)TSTEPS);
    feat[((size_t)gB * 2 + rr) * 128 + q * 32 + hl] = fcb * (1.0f / (float)TSTEPS);
  }
#undef ISSUE
#undef WRITESTG
#undef DO_CELLS
#undef DRAIN_FLAG
#undef GPOLL
#undef SPIN4
}

// ============================================================
// K3: head — gesture + (binary) domain_hidden -> domain
// ============================================================
__global__ __launch_bounds__(128) void k3_head(const float* __restrict__ feat,
    const float* __restrict__ gw, const float* __restrict__ gb,
    const float* __restrict__ d1w, const float* __restrict__ d1b,
    const float* __restrict__ thrdp,
    const float* __restrict__ d2w, const float* __restrict__ d2b,
    float* __restrict__ out) {
  __shared__ float fL[128];
  __shared__ float dh[64];
  const int b = blockIdx.x, t = threadIdx.x;
  fL[t] = feat[b * 128 + t];
  __syncthreads();
  if (t < 64) {
    float s = d1b[t];
    for (int k = 0; k < 128; ++k) s += d1w[t * 128 + k] * fL[k];
    dh[t] = (s - thrdp[0] > 0.0f) ? 1.0f : 0.0f;
  }
  __syncthreads();
  if (t < 8) {
    float s = gb[t];
    for (int k = 0; k < 128; ++k) s += gw[t * 128 + k] * fL[k];
    out[b * 8 + t] = s;
  }
  if (t >= 64 && t < 74) {
    const int o = t - 64;
    float s = d2b[o];
    for (int k = 0; k < 64; ++k) s += d2w[o * 64 + k] * dh[k];
    out[2048 + b * 10 + o] = s;
  }
}

// ============================================================
extern "C" void kernel_launch(void* const* d_in, const int* in_sizes, int n_in,
                              void* d_out, int out_size, void* d_ws, size_t ws_size,
                              hipStream_t stream) {
  const float* x      = (const float*)d_in[0];
  const float* conv_w = (const float*)d_in[1];
  const float* bn_g   = (const float*)d_in[2];
  const float* bn_b   = (const float*)d_in[3];
  const float* thrl1  = (const float*)d_in[4];
  const float* w_ih1  = (const float*)d_in[5];
  const float* w_hh1  = (const float*)d_in[6];
  const float* b_ih1  = (const float*)d_in[7];
  const float* b_hh1  = (const float*)d_in[8];
  const float* thr1   = (const float*)d_in[9];
  const float* w_ih2  = (const float*)d_in[10];
  const float* w_hh2  = (const float*)d_in[11];
  const float* b_ih2  = (const float*)d_in[12];
  const float* b_hh2  = (const float*)d_in[13];
  const float* thr2   = (const float*)d_in[14];
  const float* fc_g_w = (const float*)d_in[15];
  const float* fc_g_b = (const float*)d_in[16];
  const float* fc_d1w = (const float*)d_in[17];
  const float* fc_d1b = (const float*)d_in[18];
  const float* thrdom = (const float*)d_in[19];
  const float* fc_d2w = (const float*)d_in[20];
  const float* fc_d2b = (const float*)d_in[21];
  float* out = (float*)d_out;
  char* ws = (char*)d_ws;

  k0_zero<<<(ZERO_WORDS + 255) / 256, 256, 0, stream>>>((unsigned*)ws);
  k1_stats<<<dim3(NB, 9), 256, 0, stream>>>(x, conv_w, (float*)(ws + OFF_PART));
  k1b_reduce<<<1, 256, 0, stream>>>(bn_g, bn_b, (const float*)(ws + OFF_PART),
                                    (float*)(ws + OFF_AB));
  k2_spike<<<dim3(NB, 9), 256, 0, stream>>>(x, conv_w, thrl1,
                                            (const float*)(ws + OFF_AB),
                                            (unsigned long long*)(ws + OFF_MASK));
  // 96KB dynamic LDS: exactly 1 block/CU, 256 blocks on 256 CUs
  kp_fused<<<256, 512, 98304, stream>>>(ws, w_ih1, w_hh1, b_ih1, b_hh1, thr1,
                                        w_ih2, w_hh2, b_ih2, b_hh2, thr2);
  k3_head<<<NB, 128, 0, stream>>>((const float*)(ws + OFF_FEAT), fc_g_w, fc_g_b,
                                  fc_d1w, fc_d1b, thrdom, fc_d2w, fc_d2b, out);
}

// Round 10
// 21166.371 us; speedup vs baseline: 1.4616x; 1.4616x over previous
//
#include <hip/hip_runtime.h>
#include <cstdint>
#include <cstddef>

typedef unsigned long long u64;

// ---------------- problem constants ----------------
#define TSTEPS 2000
#define NB     256      // batch
#define HID    128
#define CIN    14
#define NGRP   64       // row groups
#define RG     4        // rows per group

// ---------------- workspace layout (bytes) ----------------
// State buffers are TAGGED u64 ((phase<<32)|float_bits) and OVERLAY the BN
// partials region (dead after k1b); k0z re-zeroes them before kp.
#define OFF_FEAT  0ull                      // [256][128] f32 = 131072
#define OFF_AB    131072ull                 // a[64], b[64] = 512
#define OFF_M1    131584ull                 // u64 [2][64][512]  = 524288
#define OFF_M2    (OFF_M1 + 524288ull)      // u64 [2][64][512]  = 524288
#define OFF_SPK   (OFF_M2 + 524288ull)      // u64 [2][64][16]   = 16384
#define OFF_PART  131584ull                 // f32 [2304][64][2] = 1179648 (alias)
#define OFF_MASK  (OFF_PART + 1179648ull)   // u64 [2000][256]   = 4096000
#define STATE_WORDS 266240                  // (2*524288+16384)/4 u32 words

// ============================================================
// K0z: zero tagged-state region (runs AFTER k1b consumed PART)
// ============================================================
__global__ __launch_bounds__(256) void k0z(unsigned* st) {
  int i = blockIdx.x * 256 + threadIdx.x;
  if (i < STATE_WORDS) st[i] = 0u;
}

// ============================================================
// K1: conv1d -> per-(b,tile) partial sum/sumsq for BN
// ============================================================
__global__ __launch_bounds__(256) void k1_stats(const float* __restrict__ x,
                                                const float* __restrict__ cw,
                                                float* __restrict__ part) {
  __shared__ float xLds[244 * CIN];
  __shared__ float cwLds[64 * 70];
  __shared__ float red[2][4][64];
  const int b = blockIdx.x, tile = blockIdx.y;
  const int base = tile * 240;
  for (int f = threadIdx.x; f < 244 * CIN; f += 256) {
    int u = f / CIN, ci = f - u * CIN;
    int tp = base + u - 2;
    xLds[f] = (tp >= 0 && tp < TSTEPS) ? x[((size_t)tp * NB + b) * CIN + ci] : 0.0f;
  }
  for (int f = threadIdx.x; f < 64 * 70; f += 256) cwLds[f] = cw[f];
  __syncthreads();

  const int co = threadIdx.x & 63, tq = threadIdx.x >> 6;
  float cwr[70];
#pragma unroll
  for (int s = 0; s < 70; ++s) cwr[s] = cwLds[co * 70 + s];
  float xw[5][CIN];
  const int u0 = tq * 60;
#pragma unroll
  for (int r = 0; r < 4; ++r)
#pragma unroll
    for (int ci = 0; ci < CIN; ++ci) xw[r][ci] = xLds[(u0 + r) * CIN + ci];

  float s1 = 0.0f, s2 = 0.0f;
  const int tbase = base + tq * 60;
  for (int i5 = 0; i5 < 60; i5 += 5) {
#pragma unroll
    for (int s = 0; s < 5; ++s) {
#pragma unroll
      for (int ci = 0; ci < CIN; ++ci)
        xw[(s + 4) % 5][ci] = xLds[(u0 + i5 + s + 4) * CIN + ci];
      float y = 0.0f;
#pragma unroll
      for (int kk = 0; kk < 5; ++kk)
#pragma unroll
        for (int ci = 0; ci < CIN; ++ci)
          y += xw[(s + kk) % 5][ci] * cwr[ci * 5 + kk];
      if (tbase + i5 + s < TSTEPS) { s1 += y; s2 += y * y; }
    }
  }
  red[0][tq][co] = s1; red[1][tq][co] = s2;
  __syncthreads();
  if (threadIdx.x < 64) {
    float a1 = red[0][0][co] + red[0][1][co] + red[0][2][co] + red[0][3][co];
    float a2 = red[1][0][co] + red[1][1][co] + red[1][2][co] + red[1][3][co];
    int blk = tile * NB + b;
    part[blk * 128 + co * 2 + 0] = a1;
    part[blk * 128 + co * 2 + 1] = a2;
  }
}

// K1b: deterministic fixed-order reduction of partials -> a[co], b[co]
__global__ __launch_bounds__(256) void k1b_reduce(const float* __restrict__ gamma,
                           const float* __restrict__ beta,
                           const float* __restrict__ part, float* __restrict__ ab) {
  __shared__ float red[2][4][64];
  const int co = threadIdx.x & 63, pt = threadIdx.x >> 6;
  float s1 = 0.0f, s2 = 0.0f;
  for (int blk = pt * 576; blk < pt * 576 + 576; ++blk) {
    s1 += part[blk * 128 + co * 2 + 0];
    s2 += part[blk * 128 + co * 2 + 1];
  }
  red[0][pt][co] = s1; red[1][pt][co] = s2;
  __syncthreads();
  if (threadIdx.x < 64) {
    float a1 = red[0][0][co] + red[0][1][co] + red[0][2][co] + red[0][3][co];
    float a2 = red[1][0][co] + red[1][1][co] + red[1][2][co] + red[1][3][co];
    const float N = (float)TSTEPS * (float)NB;
    float mu = a1 / N;
    float var = a2 / N - mu * mu;
    float rstd = 1.0f / sqrtf(var + 1e-5f);
    float a = gamma[co] * rstd;
    ab[co] = a;
    ab[64 + co] = beta[co] - mu * a;
  }
}

// ============================================================
// K2: conv1d -> BN -> spike -> pack 64 channel bits into u64 per (t,b)
// ============================================================
__global__ __launch_bounds__(256) void k2_spike(const float* __restrict__ x,
                                                const float* __restrict__ cw,
                                                const float* __restrict__ thrp,
                                                const float* __restrict__ ab,
                                                u64* __restrict__ masks) {
  __shared__ float xLds[244 * CIN];
  __shared__ float cwLds[64 * 70];
  const int b = blockIdx.x, tile = blockIdx.y;
  const int base = tile * 240;
  for (int f = threadIdx.x; f < 244 * CIN; f += 256) {
    int u = f / CIN, ci = f - u * CIN;
    int tp = base + u - 2;
    xLds[f] = (tp >= 0 && tp < TSTEPS) ? x[((size_t)tp * NB + b) * CIN + ci] : 0.0f;
  }
  for (int f = threadIdx.x; f < 64 * 70; f += 256) cwLds[f] = cw[f];
  __syncthreads();

  const int co = threadIdx.x & 63, tq = threadIdx.x >> 6;
  const float thr = thrp[0];
  const float aC = ab[co], bC = ab[64 + co];
  float cwr[70];
#pragma unroll
  for (int s = 0; s < 70; ++s) cwr[s] = cwLds[co * 70 + s];
  float xw[5][CIN];
  const int u0 = tq * 60;
#pragma unroll
  for (int r = 0; r < 4; ++r)
#pragma unroll
    for (int ci = 0; ci < CIN; ++ci) xw[r][ci] = xLds[(u0 + r) * CIN + ci];

  const int tbase = base + tq * 60;
  for (int i5 = 0; i5 < 60; i5 += 5) {
#pragma unroll
    for (int s = 0; s < 5; ++s) {
#pragma unroll
      for (int ci = 0; ci < CIN; ++ci)
        xw[(s + 4) % 5][ci] = xLds[(u0 + i5 + s + 4) * CIN + ci];
      float y = 0.0f;
#pragma unroll
      for (int kk = 0; kk < 5; ++kk)
#pragma unroll
        for (int ci = 0; ci < CIN; ++ci)
          y += xw[(s + kk) % 5][ci] * cwr[ci * 5 + kk];
      int t = tbase + i5 + s;
      if (t < TSTEPS) {
        float bn = y * aC + bC;
        u64 m = __ballot(bn - thr > 0.0f);  // lane i = channel i
        if (co == 0) masks[(size_t)t * NB + b] = m;
      }
    }
  }
}

// ============================================================
// KP: fused persistent two-layer SLSTM, r4 structure, SELF-SYNCING DATA:
// every exchanged word is u64 (phase_tag<<32 | float_bits). The staging
// load polls its own word's tag == p -> the load IS the barrier. No
// flags, no vmcnt-drain, no poll round trip; 3 syncthreads/phase.
// Double-buffered by parity; producer can't lead a consumer of its data
// by >=2 phases (it blocks on that consumer's output), so overwrite
// before consumption is impossible. Arithmetic bit-identical to r4.
// ============================================================
__device__ __forceinline__ u64 ld_agent(const u64* p_) {
  return __hip_atomic_load(p_, __ATOMIC_RELAXED, __HIP_MEMORY_SCOPE_AGENT);
}
__device__ __forceinline__ void st_agent(u64* p_, u64 v) {
  __hip_atomic_store(p_, v, __ATOMIC_RELAXED, __HIP_MEMORY_SCOPE_AGENT);
}

__global__ __launch_bounds__(512) void kp_fused(char* ws,
    const float* __restrict__ w_ih1, const float* __restrict__ w_hh1,
    const float* __restrict__ b_ih1, const float* __restrict__ b_hh1,
    const float* __restrict__ thr1p,
    const float* __restrict__ w_ih2, const float* __restrict__ w_hh2,
    const float* __restrict__ b_ih2, const float* __restrict__ b_hh2,
    const float* __restrict__ thr2p) {
  __shared__ __align__(16) float A1[192 * 4];   // [k][4 r]
  __shared__ __align__(16) float A2[256 * 4];
  __shared__ float gate1L[128 * 5];             // stride 5 breaks bank pattern
  __shared__ float gate2L[128 * 5];
  __shared__ float biasL1[128], biasL2[128];

  const int tid = threadIdx.x;
  const int bid = blockIdx.x;
  const int g = bid & 63;          // group; peers bid = g+64k
  const int q = bid >> 6;          // h-quarter 0..3
  const int lane = tid & 63, wv = tid >> 6;
  const int idx = lane & 15, kq = lane >> 4;
  const int a = idx & 3, hlq = idx >> 2;
  const int hl = hlq * 8 + wv;
  const int j = a * 32 + hl;                 // gate row within block (0..127)
  const int grow = a * 128 + q * 32 + hl;    // global weight row (0..511)

  u64* m1ws = (u64*)(ws + OFF_M1);
  u64* m2ws = (u64*)(ws + OFF_M2);
  u64* spkw = (u64*)(ws + OFF_SPK);
  float* feat = (float*)(ws + OFF_FEAT);
  const u64* masks = (const u64*)(ws + OFF_MASK);

  // ---- one-time: weights -> registers (interleaved k-partition, = r4) ----
  float wr1[48];
#pragma unroll
  for (int i = 0; i < 48; ++i) {
    int k = ((i >> 1) << 3) + (kq << 1) + (i & 1);   // k = 8m + 2kq + b
    wr1[i] = (k < 64) ? w_ih1[grow * 64 + k] : w_hh1[grow * 128 + (k - 64)];
  }
  float wr2[64];
#pragma unroll
  for (int i = 0; i < 64; ++i) {
    int k = ((i >> 1) << 3) + (kq << 1) + (i & 1);
    wr2[i] = (k < 128) ? w_ih2[grow * 128 + k] : w_hh2[grow * 128 + (k - 128)];
  }
  if (tid < 128) {
    int aa = tid >> 5, h2 = tid & 31;
    int gr = aa * 128 + q * 32 + h2;
    biasL1[tid] = b_ih1[gr] + b_hh1[gr];
    biasL2[tid] = b_ih2[gr] + b_hh2[gr];
  }
  const float thr1 = thr1p[0], thr2 = thr2p[0];
  const int cr = tid >> 5, chl = tid & 31;   // cell mapping for tid<128
  float syn1 = 0.0f, mem1 = 0.0f, syn2 = 0.0f, mem2 = 0.0f, facc = 0.0f;
  __syncthreads();

  // conv-spike mask for step 0 (row = tid&3)
  u64 mrow = masks[(size_t)0 * NB + g * RG + (tid & 3)];

  for (int p = 0; p <= TSTEPS; ++p) {
    const int rb1 = (p + 1) & 1;   // parity of p-1 data
    const int wb = p & 1;          // parity of p data (also m2(p-2) read parity)
    const unsigned tagp = (unsigned)p;
    const u64 wtag = ((u64)(p + 1)) << 32;

    // ---- tagged staging: issue all three polled loads together ----
    const u64* p1 = m1ws + (size_t)(rb1 * 64 + g) * 512 + tid;          // m1(p-1)
    const u64* ps = spkw + (size_t)(rb1 * 64 + g) * 16 + (tid & 3) * 4 + (tid >> 7);
    const u64* p2 = m2ws + (size_t)(wb * 64 + g) * 512 + tid;           // m2(p-2)
    u64 w1 = ld_agent(p1);
    u64 wsp = ld_agent(ps);
    u64 w2 = ld_agent(p2);
    while ((unsigned)(w1 >> 32) < tagp) { __builtin_amdgcn_s_sleep(1); w1 = ld_agent(p1); }
    while ((unsigned)(wsp >> 32) < tagp) { __builtin_amdgcn_s_sleep(1); wsp = ld_agent(ps); }
    while ((unsigned)(w2 >> 32) < tagp) { __builtin_amdgcn_s_sleep(1); w2 = ld_agent(p2); }
    if (tid < 256) A1[tid] = (float)((mrow >> (tid >> 2)) & 1ull);      // conv bits
    A1[256 + tid] = __uint_as_float((unsigned)w1);                      // m1(p-1)
    A2[tid] = (float)(((unsigned)wsp >> ((tid >> 2) & 31)) & 1u);       // spk1(p-1)
    A2[512 + tid] = __uint_as_float((unsigned)w2);                      // m2(p-2)
    if (p + 1 < TSTEPS) mrow = masks[(size_t)(p + 1) * NB + g * RG + (tid & 3)];
    __syncthreads();   // sync1: staging visible

    // ---- GEMM1: K=192, k-split over kq (= r4) ----
    {
      float ac[4][4];
#pragma unroll
      for (int aa = 0; aa < 4; ++aa)
#pragma unroll
        for (int r = 0; r < 4; ++r) ac[aa][r] = 0.0f;
      const float* Ab = A1 + (kq << 3);
#pragma unroll
      for (int m = 0; m < 24; ++m) {
#pragma unroll
        for (int b2 = 0; b2 < 2; ++b2) {
          float4 av = *(const float4*)(Ab + m * 32 + b2 * 4);
          float w = wr1[m * 2 + b2];
          ac[0][0] += w * av.x; ac[0][1] += w * av.y;
          ac[0][2] += w * av.z; ac[0][3] += w * av.w;
        }
      }
      // NOTE: r4 used acc per (a) via j mapping; replicate exactly:
      // r4's single-j GEMM accumulated ac0..ac3 for THIS thread's j row.
      // (ac[0][*] above is that accumulator.)
#pragma unroll
      for (int r = 0; r < 4; ++r) {
        float v = ac[0][r];
        v += __shfl_xor(v, 16); v += __shfl_xor(v, 32);
        ac[0][r] = v;
      }
      if (kq == 0) {
        gate1L[j * 5 + 0] = ac[0][0]; gate1L[j * 5 + 1] = ac[0][1];
        gate1L[j * 5 + 2] = ac[0][2]; gate1L[j * 5 + 3] = ac[0][3];
      }
    }
    // ---- GEMM2: K=256 (= r4) ----
    {
      float ac0 = 0.0f, ac1 = 0.0f, ac2 = 0.0f, ac3 = 0.0f;
      const float* Ab = A2 + (kq << 3);
#pragma unroll
      for (int m = 0; m < 32; ++m) {
#pragma unroll
        for (int b2 = 0; b2 < 2; ++b2) {
          float4 av = *(const float4*)(Ab + m * 32 + b2 * 4);
          float w = wr2[m * 2 + b2];
          ac0 += w * av.x; ac1 += w * av.y; ac2 += w * av.z; ac3 += w * av.w;
        }
      }
      ac0 += __shfl_xor(ac0, 16); ac1 += __shfl_xor(ac1, 16);
      ac2 += __shfl_xor(ac2, 16); ac3 += __shfl_xor(ac3, 16);
      ac0 += __shfl_xor(ac0, 32); ac1 += __shfl_xor(ac1, 32);
      ac2 += __shfl_xor(ac2, 32); ac3 += __shfl_xor(ac3, 32);
      if (kq == 0) {
        gate2L[j * 5 + 0] = ac0; gate2L[j * 5 + 1] = ac1;
        gate2L[j * 5 + 2] = ac2; gate2L[j * 5 + 3] = ac3;
      }
    }
    __syncthreads();   // sync2: gates visible

    // ---- cell1 (step p): publish m1(p), spk1(p) tagged p+1 ----
    if (tid < 128 && p < TSTEPS) {
      float g0 = biasL1[chl]       + gate1L[(chl) * 5 + cr];
      float g1 = biasL1[32 + chl]  + gate1L[(32 + chl) * 5 + cr];
      float g2 = biasL1[64 + chl]  + gate1L[(64 + chl) * 5 + cr];
      float g3 = biasL1[96 + chl]  + gate1L[(96 + chl) * 5 + cr];
      float rst = (mem1 - thr1 > 0.0f) ? thr1 : 0.0f;
      float ig = 1.0f / (1.0f + expf(-g0));
      float fg = 1.0f / (1.0f + expf(-g1));
      float gg = tanhf(g2);
      float og = 1.0f / (1.0f + expf(-g3));
      float cn = fg * syn1 + ig * gg;
      float mn = og * tanhf(cn) - rst;
      syn1 = cn; mem1 = mn;
      st_agent(&m1ws[(size_t)(wb * 64 + g) * 512 + (q * 32 + chl) * 4 + cr],
               wtag | (u64)__float_as_uint(mn));
      u64 bal = __ballot(mn - thr1 > 0.0f);
      if (lane == 0)
        st_agent(&spkw[(size_t)(wb * 64 + g) * 16 + (wv * 2 + 0) * 4 + q],
                 wtag | (bal & 0xffffffffull));
      if (lane == 32)
        st_agent(&spkw[(size_t)(wb * 64 + g) * 16 + (wv * 2 + 1) * 4 + q],
                 wtag | (bal >> 32));
    }
    // ---- cell2 (step p-1): publish m2(p-1) tagged p+1; seed at p==0 ----
    if (tid < 128) {
      if (p >= 1 && p <= TSTEPS) {
        float g0 = biasL2[chl]       + gate2L[(chl) * 5 + cr];
        float g1 = biasL2[32 + chl]  + gate2L[(32 + chl) * 5 + cr];
        float g2 = biasL2[64 + chl]  + gate2L[(64 + chl) * 5 + cr];
        float g3 = biasL2[96 + chl]  + gate2L[(96 + chl) * 5 + cr];
        float rst = (mem2 - thr2 > 0.0f) ? thr2 : 0.0f;
        float ig = 1.0f / (1.0f + expf(-g0));
        float fg = 1.0f / (1.0f + expf(-g1));
        float gg = tanhf(g2);
        float og = 1.0f / (1.0f + expf(-g3));
        float cn = fg * syn2 + ig * gg;
        float mn = og * tanhf(cn) - rst;
        syn2 = cn; mem2 = mn;
        st_agent(&m2ws[(size_t)(rb1 * 64 + g) * 512 + (q * 32 + chl) * 4 + cr],
                 wtag | (u64)__float_as_uint(mn));
        facc += mn;
      } else if (p == 0) {  // seed m2(-1)=0 with tag 1 so phase 1 polls pass
        st_agent(&m2ws[(size_t)(rb1 * 64 + g) * 512 + (q * 32 + chl) * 4 + cr],
                 wtag);
      }
    }
    __syncthreads();   // sync3: cells done before A/gates rewritten
  }

  if (tid < 128)
    feat[(g * RG + cr) * 128 + q * 32 + chl] = facc * (1.0f / (float)TSTEPS);
}

// ============================================================
// K3: head — gesture + (binary) domain_hidden -> domain
// ============================================================
__global__ __launch_bounds__(128) void k3_head(const float* __restrict__ feat,
    const float* __restrict__ gw, const float* __restrict__ gb,
    const float* __restrict__ d1w, const float* __restrict__ d1b,
    const float* __restrict__ thrdp,
    const float* __restrict__ d2w, const float* __restrict__ d2b,
    float* __restrict__ out) {
  __shared__ float fL[128];
  __shared__ float dh[64];
  const int b = blockIdx.x, t = threadIdx.x;
  fL[t] = feat[b * 128 + t];
  __syncthreads();
  if (t < 64) {
    float s = d1b[t];
    for (int k = 0; k < 128; ++k) s += d1w[t * 128 + k] * fL[k];
    dh[t] = (s - thrdp[0] > 0.0f) ? 1.0f : 0.0f;
  }
  __syncthreads();
  if (t < 8) {
    float s = gb[t];
    for (int k = 0; k < 128; ++k) s += gw[t * 128 + k] * fL[k];
    out[b * 8 + t] = s;
  }
  if (t >= 64 && t < 74) {
    const int o = t - 64;
    float s = d2b[o];
    for (int k = 0; k < 64; ++k) s += d2w[o * 64 + k] * dh[k];
    out[2048 + b * 10 + o] = s;
  }
}

// ============================================================
extern "C" void kernel_launch(void* const* d_in, const int* in_sizes, int n_in,
                              void* d_out, int out_size, void* d_ws, size_t ws_size,
                              hipStream_t stream) {
  const float* x      = (const float*)d_in[0];
  const float* conv_w = (const float*)d_in[1];
  const float* bn_g   = (const float*)d_in[2];
  const float* bn_b   = (const float*)d_in[3];
  const float* thrl1  = (const float*)d_in[4];
  const float* w_ih1  = (const float*)d_in[5];
  const float* w_hh1  = (const float*)d_in[6];
  const float* b_ih1  = (const float*)d_in[7];
  const float* b_hh1  = (const float*)d_in[8];
  const float* thr1   = (const float*)d_in[9];
  const float* w_ih2  = (const float*)d_in[10];
  const float* w_hh2  = (const float*)d_in[11];
  const float* b_ih2  = (const float*)d_in[12];
  const float* b_hh2  = (const float*)d_in[13];
  const float* thr2   = (const float*)d_in[14];
  const float* fc_g_w = (const float*)d_in[15];
  const float* fc_g_b = (const float*)d_in[16];
  const float* fc_d1w = (const float*)d_in[17];
  const float* fc_d1b = (const float*)d_in[18];
  const float* thrdom = (const float*)d_in[19];
  const float* fc_d2w = (const float*)d_in[20];
  const float* fc_d2b = (const float*)d_in[21];
  float* out = (float*)d_out;
  char* ws = (char*)d_ws;

  k1_stats<<<dim3(NB, 9), 256, 0, stream>>>(x, conv_w, (float*)(ws + OFF_PART));
  k1b_reduce<<<1, 256, 0, stream>>>(bn_g, bn_b, (const float*)(ws + OFF_PART),
                                    (float*)(ws + OFF_AB));
  k2_spike<<<dim3(NB, 9), 256, 0, stream>>>(x, conv_w, thrl1,
                                            (const float*)(ws + OFF_AB),
                                            (u64*)(ws + OFF_MASK));
  // zero the tagged-state region (overlays PART, which is now dead)
  k0z<<<(STATE_WORDS + 255) / 256, 256, 0, stream>>>((unsigned*)(ws + OFF_M1));
  kp_fused<<<NGRP * 4, 512, 0, stream>>>(ws, w_ih1, w_hh1, b_ih1, b_hh1, thr1,
                                         w_ih2, w_hh2, b_ih2, b_hh2, thr2);
  k3_head<<<NB, 128, 0, stream>>>((const float*)(ws + OFF_FEAT), fc_g_w, fc_g_b,
                                  fc_d1w, fc_d1b, thrdom, fc_d2w, fc_d2b, out);
}